// Round 2
// baseline (2881.098 us; speedup 1.0000x reference)
//
#include <hip/hip_runtime.h>

#define D 128

// out = relu( (sum_e a_e * x[src_e]) @ W + y + bias )   [linearity of GEMM]
// d_out doubles as the [N,128] fp32 aggregation buffer -> zero scratch needed.

// ---------------------------------------------------------------------------
// Zero the accumulator (d_out). Harness poisons d_out to 0xAA; we need zeros.
// ---------------------------------------------------------------------------
__global__ __launch_bounds__(256) void zero_kernel(float4* __restrict__ out, int n4) {
  int i = blockIdx.x * 256 + threadIdx.x;
  if (i < n4) out[i] = make_float4(0.f, 0.f, 0.f, 0.f);
}

// ---------------------------------------------------------------------------
// Edge scatter: 32 lanes per edge, one float4 (4 cols) per lane.
// Gathers x[src] (51.2 MB table, LLC-resident), atomicAdd a*x into out[dst].
// ---------------------------------------------------------------------------
__global__ __launch_bounds__(256) void scatter_kernel(
    const float* __restrict__ x, const int* __restrict__ src,
    const int* __restrict__ dst, const float* __restrict__ adj,
    float* __restrict__ out, int nE) {
  int tid = blockIdx.x * 256 + threadIdx.x;
  int e = tid >> 5;
  int q = tid & 31;
  if (e >= nE) return;
  int s = src[e];
  int d = dst[e];
  float a = adj[e];
  float4 v = ((const float4*)x)[(size_t)s * 32 + q];
  float* o = out + (size_t)d * D + q * 4;
  atomicAdd(o + 0, v.x * a);
  atomicAdd(o + 1, v.y * a);
  atomicAdd(o + 2, v.z * a);
  atomicAdd(o + 3, v.w * a);
}

// ---------------------------------------------------------------------------
// Fused in-place GEMM + epilogue: out[r,:] = relu(out[r,:] @ W + y[r,:] + b).
// Row-local: each block owns 32 rows, stages them in LDS, writes back the
// same 32 rows -> no cross-block hazard. W (64KB) + tile (16KB) in LDS.
// Thread: cg=tid&31 -> 4 cols, rs=tid>>5 -> 4 rows (stride 8).
// ---------------------------------------------------------------------------
__global__ __launch_bounds__(256) void gemm_fused_kernel(
    float* __restrict__ out, const float* __restrict__ w,
    const float* __restrict__ y, const float* __restrict__ bias, int nrows) {
  __shared__ float sW[D * D];   // 64 KB
  __shared__ float sA[32 * D];  // 16 KB
  const int tid = threadIdx.x;
  const int row0 = blockIdx.x * 32;

  const float4* w4 = (const float4*)w;
  float4* sW4 = (float4*)sW;
  for (int i = tid; i < D * D / 4; i += 256) sW4[i] = w4[i];

  const int nrow_blk = min(32, nrows - row0);
  const float4* out4_base = (const float4*)(out + (size_t)row0 * D);
  float4* sA4 = (float4*)sA;
  for (int i = tid; i < nrow_blk * 32; i += 256) sA4[i] = out4_base[i];
  __syncthreads();

  const int cg = tid & 31;   // col group: cols cg*4 .. cg*4+3
  const int rs = tid >> 5;   // row slot: rows rs, rs+8, rs+16, rs+24

  float4 acc[4];
#pragma unroll
  for (int r = 0; r < 4; ++r) acc[r] = make_float4(0.f, 0.f, 0.f, 0.f);

#pragma unroll 4
  for (int k4 = 0; k4 < 32; ++k4) {
    float4 wv0 = sW4[(k4 * 4 + 0) * 32 + cg];
    float4 wv1 = sW4[(k4 * 4 + 1) * 32 + cg];
    float4 wv2 = sW4[(k4 * 4 + 2) * 32 + cg];
    float4 wv3 = sW4[(k4 * 4 + 3) * 32 + cg];
#pragma unroll
    for (int r = 0; r < 4; ++r) {
      float4 xv = sA4[(rs + r * 8) * 32 + k4];
      acc[r].x = fmaf(xv.x, wv0.x, acc[r].x);
      acc[r].y = fmaf(xv.x, wv0.y, acc[r].y);
      acc[r].z = fmaf(xv.x, wv0.z, acc[r].z);
      acc[r].w = fmaf(xv.x, wv0.w, acc[r].w);
      acc[r].x = fmaf(xv.y, wv1.x, acc[r].x);
      acc[r].y = fmaf(xv.y, wv1.y, acc[r].y);
      acc[r].z = fmaf(xv.y, wv1.z, acc[r].z);
      acc[r].w = fmaf(xv.y, wv1.w, acc[r].w);
      acc[r].x = fmaf(xv.z, wv2.x, acc[r].x);
      acc[r].y = fmaf(xv.z, wv2.y, acc[r].y);
      acc[r].z = fmaf(xv.z, wv2.z, acc[r].z);
      acc[r].w = fmaf(xv.z, wv2.w, acc[r].w);
      acc[r].x = fmaf(xv.w, wv3.x, acc[r].x);
      acc[r].y = fmaf(xv.w, wv3.y, acc[r].y);
      acc[r].z = fmaf(xv.w, wv3.z, acc[r].z);
      acc[r].w = fmaf(xv.w, wv3.w, acc[r].w);
    }
  }

  const float4* y4 = (const float4*)y;
  const float4* b4 = (const float4*)bias;
  float4* o4 = (float4*)out;
  float4 bv = b4[cg];
#pragma unroll
  for (int r = 0; r < 4; ++r) {
    int row = row0 + rs + r * 8;
    if (row < nrows) {
      float4 yv = y4[(size_t)row * 32 + cg];
      float4 res;
      res.x = fmaxf(acc[r].x + yv.x + bv.x, 0.f);
      res.y = fmaxf(acc[r].y + yv.y + bv.y, 0.f);
      res.z = fmaxf(acc[r].z + yv.z + bv.z, 0.f);
      res.w = fmaxf(acc[r].w + yv.w + bv.w, 0.f);
      o4[(size_t)row * 32 + cg] = res;
    }
  }
}

extern "C" void kernel_launch(void* const* d_in, const int* in_sizes, int n_in,
                              void* d_out, int out_size, void* d_ws, size_t ws_size,
                              hipStream_t stream) {
  const float* x    = (const float*)d_in[0];
  const float* y    = (const float*)d_in[1];
  const int*   esrc = (const int*)d_in[2];
  const int*   edst = (const int*)d_in[3];
  const float* adj  = (const float*)d_in[4];
  const float* w    = (const float*)d_in[5];
  const float* bias = (const float*)d_in[6];
  float* out = (float*)d_out;

  const int nNodes = in_sizes[0] / D;
  const int nE = in_sizes[2];
  const int n4 = nNodes * (D / 4);

  zero_kernel<<<(n4 + 255) / 256, 256, 0, stream>>>((float4*)out, n4);
  scatter_kernel<<<((nE * 32) + 255) / 256, 256, 0, stream>>>(
      x, esrc, edst, adj, out, nE);
  gemm_fused_kernel<<<(nNodes + 31) / 32, 256, 0, stream>>>(out, w, y, bias, nNodes);
}

// Round 3
// 508.566 us; speedup vs baseline: 5.6651x; 5.6651x over previous
//
#include <hip/hip_runtime.h>

#define D 128
#define CHUNK 1024  // elements scanned per block (256 thr x 4)

// out = relu( (sum_e a_e * x[src_e]) @ W + y + bias )   [linearity of GEMM]
// Round 3: counting-sort edges by dst each launch -> atomic-free gather.

// ============================ CSR build ====================================
__global__ __launch_bounds__(256) void zero_counts_kernel(int* __restrict__ c, int n) {
  int i = blockIdx.x * 256 + threadIdx.x;
  if (i < n) c[i] = 0;
}

__global__ __launch_bounds__(256) void hist_kernel(
    const int* __restrict__ dst, int* __restrict__ counts, int nE) {
  int e = blockIdx.x * 256 + threadIdx.x;
  if (e < nE) atomicAdd(&counts[dst[e]], 1);
}

__global__ __launch_bounds__(256) void scan_partial_kernel(
    const int* __restrict__ counts, int* __restrict__ chunk_sum, int n) {
  __shared__ int sdata[256];
  int b = blockIdx.x, t = threadIdx.x;
  int base = b * CHUNK + t * 4;
  int s = 0;
#pragma unroll
  for (int k = 0; k < 4; ++k) {
    int i = base + k;
    if (i < n) s += counts[i];
  }
  sdata[t] = s;
  __syncthreads();
  for (int off = 128; off > 0; off >>= 1) {
    if (t < off) sdata[t] += sdata[t + off];
    __syncthreads();
  }
  if (t == 0) chunk_sum[b] = sdata[0];
}

__global__ void scan_chunks_kernel(const int* __restrict__ chunk_sum,
                                   int* __restrict__ chunk_off,
                                   int* __restrict__ row_start, int nchunks, int n) {
  if (threadIdx.x == 0 && blockIdx.x == 0) {
    int run = 0;
    for (int i = 0; i < nchunks; ++i) {
      chunk_off[i] = run;
      run += chunk_sum[i];
    }
    row_start[n] = run;
  }
}

__global__ __launch_bounds__(256) void scan_final_kernel(
    const int* __restrict__ counts, const int* __restrict__ chunk_off,
    int* __restrict__ row_start, int* __restrict__ cursor, int n) {
  __shared__ int sdata[256];
  int b = blockIdx.x, t = threadIdx.x;
  int base = b * CHUNK + t * 4;
  int c[4] = {0, 0, 0, 0};
#pragma unroll
  for (int k = 0; k < 4; ++k) {
    int i = base + k;
    if (i < n) c[k] = counts[i];
  }
  int tsum = c[0] + c[1] + c[2] + c[3];
  sdata[t] = tsum;
  __syncthreads();
  // Hillis-Steele inclusive scan over 256 thread sums
  for (int off = 1; off < 256; off <<= 1) {
    int v = (t >= off) ? sdata[t - off] : 0;
    __syncthreads();
    sdata[t] += v;
    __syncthreads();
  }
  int run = sdata[t] - tsum + chunk_off[b];  // exclusive prefix
#pragma unroll
  for (int k = 0; k < 4; ++k) {
    int i = base + k;
    if (i < n) {
      row_start[i] = run;
      cursor[i] = run;
      run += c[k];
    }
  }
}

__global__ __launch_bounds__(256) void scatter_sort_kernel(
    const int* __restrict__ src, const int* __restrict__ dst,
    const float* __restrict__ adj, int* __restrict__ cursor,
    int* __restrict__ ssrc, float* __restrict__ sadj, int nE) {
  int e = blockIdx.x * 256 + threadIdx.x;
  if (e >= nE) return;
  int d = dst[e];
  int pos = atomicAdd(&cursor[d], 1);
  ssrc[pos] = src[e];
  sadj[pos] = adj[e];
}

// ============================ Gather (atomic-free) =========================
// One 32-lane group per node; lane q owns cols 4q..4q+3. Per edge: one
// broadcast of (src,adj) + one coalesced 512B gather of x[src].
__global__ __launch_bounds__(256) void gather_kernel(
    const float* __restrict__ x, const int* __restrict__ row_start,
    const int* __restrict__ ssrc, const float* __restrict__ sadj,
    float* __restrict__ out, int nNodes) {
  int g = (blockIdx.x * 256 + threadIdx.x) >> 5;  // node
  int q = threadIdx.x & 31;
  if (g >= nNodes) return;
  int beg = row_start[g], end = row_start[g + 1];
  const float4* x4 = (const float4*)x;
  float4 acc = make_float4(0.f, 0.f, 0.f, 0.f);
  int j = beg;
  for (; j + 1 < end; j += 2) {
    int s0 = ssrc[j], s1 = ssrc[j + 1];
    float a0 = sadj[j], a1 = sadj[j + 1];
    float4 v0 = x4[(size_t)s0 * 32 + q];
    float4 v1 = x4[(size_t)s1 * 32 + q];
    acc.x = fmaf(a0, v0.x, acc.x); acc.y = fmaf(a0, v0.y, acc.y);
    acc.z = fmaf(a0, v0.z, acc.z); acc.w = fmaf(a0, v0.w, acc.w);
    acc.x = fmaf(a1, v1.x, acc.x); acc.y = fmaf(a1, v1.y, acc.y);
    acc.z = fmaf(a1, v1.z, acc.z); acc.w = fmaf(a1, v1.w, acc.w);
  }
  if (j < end) {
    int s0 = ssrc[j];
    float a0 = sadj[j];
    float4 v0 = x4[(size_t)s0 * 32 + q];
    acc.x = fmaf(a0, v0.x, acc.x); acc.y = fmaf(a0, v0.y, acc.y);
    acc.z = fmaf(a0, v0.z, acc.z); acc.w = fmaf(a0, v0.w, acc.w);
  }
  ((float4*)out)[(size_t)g * 32 + q] = acc;
}

// ============================ Fallback (atomic path) =======================
__global__ __launch_bounds__(256) void zero_kernel(float4* __restrict__ out, int n4) {
  int i = blockIdx.x * 256 + threadIdx.x;
  if (i < n4) out[i] = make_float4(0.f, 0.f, 0.f, 0.f);
}

__global__ __launch_bounds__(256) void scatter_atomic_kernel(
    const float* __restrict__ x, const int* __restrict__ src,
    const int* __restrict__ dst, const float* __restrict__ adj,
    float* __restrict__ out, int nE) {
  int tid = blockIdx.x * 256 + threadIdx.x;
  int e = tid >> 5;
  int q = tid & 31;
  if (e >= nE) return;
  int s = src[e];
  int d = dst[e];
  float a = adj[e];
  float4 v = ((const float4*)x)[(size_t)s * 32 + q];
  float* o = out + (size_t)d * D + q * 4;
  atomicAdd(o + 0, v.x * a);
  atomicAdd(o + 1, v.y * a);
  atomicAdd(o + 2, v.z * a);
  atomicAdd(o + 3, v.w * a);
}

// ============================ Fused GEMM epilogue ==========================
// out[r,:] = relu(out[r,:] @ W + y[r,:] + b). Row-local, in-place.
__global__ __launch_bounds__(256) void gemm_fused_kernel(
    float* __restrict__ out, const float* __restrict__ w,
    const float* __restrict__ y, const float* __restrict__ bias, int nrows) {
  __shared__ float sW[D * D];   // 64 KB
  __shared__ float sA[32 * D];  // 16 KB
  const int tid = threadIdx.x;
  const int row0 = blockIdx.x * 32;

  const float4* w4 = (const float4*)w;
  float4* sW4 = (float4*)sW;
  for (int i = tid; i < D * D / 4; i += 256) sW4[i] = w4[i];

  const int nrow_blk = min(32, nrows - row0);
  const float4* out4_base = (const float4*)(out + (size_t)row0 * D);
  float4* sA4 = (float4*)sA;
  for (int i = tid; i < nrow_blk * 32; i += 256) sA4[i] = out4_base[i];
  __syncthreads();

  const int cg = tid & 31;
  const int rs = tid >> 5;

  float4 acc[4];
#pragma unroll
  for (int r = 0; r < 4; ++r) acc[r] = make_float4(0.f, 0.f, 0.f, 0.f);

#pragma unroll 4
  for (int k4 = 0; k4 < 32; ++k4) {
    float4 wv0 = sW4[(k4 * 4 + 0) * 32 + cg];
    float4 wv1 = sW4[(k4 * 4 + 1) * 32 + cg];
    float4 wv2 = sW4[(k4 * 4 + 2) * 32 + cg];
    float4 wv3 = sW4[(k4 * 4 + 3) * 32 + cg];
#pragma unroll
    for (int r = 0; r < 4; ++r) {
      float4 xv = sA4[(rs + r * 8) * 32 + k4];
      acc[r].x = fmaf(xv.x, wv0.x, acc[r].x);
      acc[r].y = fmaf(xv.x, wv0.y, acc[r].y);
      acc[r].z = fmaf(xv.x, wv0.z, acc[r].z);
      acc[r].w = fmaf(xv.x, wv0.w, acc[r].w);
      acc[r].x = fmaf(xv.y, wv1.x, acc[r].x);
      acc[r].y = fmaf(xv.y, wv1.y, acc[r].y);
      acc[r].z = fmaf(xv.y, wv1.z, acc[r].z);
      acc[r].w = fmaf(xv.y, wv1.w, acc[r].w);
      acc[r].x = fmaf(xv.z, wv2.x, acc[r].x);
      acc[r].y = fmaf(xv.z, wv2.y, acc[r].y);
      acc[r].z = fmaf(xv.z, wv2.z, acc[r].z);
      acc[r].w = fmaf(xv.z, wv2.w, acc[r].w);
      acc[r].x = fmaf(xv.w, wv3.x, acc[r].x);
      acc[r].y = fmaf(xv.w, wv3.y, acc[r].y);
      acc[r].z = fmaf(xv.w, wv3.z, acc[r].z);
      acc[r].w = fmaf(xv.w, wv3.w, acc[r].w);
    }
  }

  const float4* y4 = (const float4*)y;
  const float4* b4 = (const float4*)bias;
  float4* o4 = (float4*)out;
  float4 bv = b4[cg];
#pragma unroll
  for (int r = 0; r < 4; ++r) {
    int row = row0 + rs + r * 8;
    if (row < nrows) {
      float4 yv = y4[(size_t)row * 32 + cg];
      float4 res;
      res.x = fmaxf(acc[r].x + yv.x + bv.x, 0.f);
      res.y = fmaxf(acc[r].y + yv.y + bv.y, 0.f);
      res.z = fmaxf(acc[r].z + yv.z + bv.z, 0.f);
      res.w = fmaxf(acc[r].w + yv.w + bv.w, 0.f);
      o4[(size_t)row * 32 + cg] = res;
    }
  }
}

extern "C" void kernel_launch(void* const* d_in, const int* in_sizes, int n_in,
                              void* d_out, int out_size, void* d_ws, size_t ws_size,
                              hipStream_t stream) {
  const float* x    = (const float*)d_in[0];
  const float* y    = (const float*)d_in[1];
  const int*   esrc = (const int*)d_in[2];
  const int*   edst = (const int*)d_in[3];
  const float* adj  = (const float*)d_in[4];
  const float* w    = (const float*)d_in[5];
  const float* bias = (const float*)d_in[6];
  float* out = (float*)d_out;

  const int nNodes = in_sizes[0] / D;
  const int nE = in_sizes[2];
  const int n4 = nNodes * (D / 4);
  const int nchunks = (nNodes + CHUNK - 1) / CHUNK;

  // workspace layout (ints)
  size_t need = (size_t)(3 * nNodes + 1 + 2 * nchunks + 2 * nE) * 4;
  if (ws_size >= need) {
    int* wsp        = (int*)d_ws;
    int* counts     = wsp;
    int* row_start  = counts + nNodes;
    int* cursor     = row_start + nNodes + 1;
    int* chunk_sum  = cursor + nNodes;
    int* chunk_off  = chunk_sum + nchunks;
    int* ssrc       = chunk_off + nchunks;
    float* sadj     = (float*)(ssrc + nE);

    zero_counts_kernel<<<(nNodes + 255) / 256, 256, 0, stream>>>(counts, nNodes);
    hist_kernel<<<(nE + 255) / 256, 256, 0, stream>>>(edst, counts, nE);
    scan_partial_kernel<<<nchunks, 256, 0, stream>>>(counts, chunk_sum, nNodes);
    scan_chunks_kernel<<<1, 64, 0, stream>>>(chunk_sum, chunk_off, row_start,
                                             nchunks, nNodes);
    scan_final_kernel<<<nchunks, 256, 0, stream>>>(counts, chunk_off, row_start,
                                                   cursor, nNodes);
    scatter_sort_kernel<<<(nE + 255) / 256, 256, 0, stream>>>(
        esrc, edst, adj, cursor, ssrc, sadj, nE);
    gather_kernel<<<(nNodes * 32 + 255) / 256, 256, 0, stream>>>(
        x, row_start, ssrc, sadj, out, nNodes);
  } else {
    // fallback: atomic scatter (proven correct in round 2)
    zero_kernel<<<(n4 + 255) / 256, 256, 0, stream>>>((float4*)out, n4);
    scatter_atomic_kernel<<<((size_t)nE * 32 + 255) / 256, 256, 0, stream>>>(
        x, esrc, edst, adj, out, nE);
  }
  gemm_fused_kernel<<<(nNodes + 31) / 32, 256, 0, stream>>>(out, w, y, bias, nNodes);
}

// Round 4
// 488.354 us; speedup vs baseline: 5.8996x; 1.0414x over previous
//
#include <hip/hip_runtime.h>

#define D 128
#define CHUNK 1024  // elements scanned per block (256 thr x 4)

// out = relu( (sum_e a_e * x[src_e]) @ W + y + bias )   [linearity of GEMM]
// Round 4: bf16 x-table (halve gather bytes), packed int2 edge records.

__device__ __forceinline__ unsigned short f2bf(float f) {
  unsigned u = __float_as_uint(f);
  unsigned r = (u + 0x7fffu + ((u >> 16) & 1u)) >> 16;  // RNE
  return (unsigned short)r;
}

// ============ K1: x -> bf16 table, fused with counts zeroing ==============
__global__ __launch_bounds__(256) void convert_zero_kernel(
    const float4* __restrict__ x4, ushort4* __restrict__ xb4, int n4,
    int* __restrict__ counts, int nN) {
  int i = blockIdx.x * 256 + threadIdx.x;
  if (i < nN) counts[i] = 0;
  if (i < n4) {
    float4 v = x4[i];
    ushort4 r;
    r.x = f2bf(v.x);
    r.y = f2bf(v.y);
    r.z = f2bf(v.z);
    r.w = f2bf(v.w);
    xb4[i] = r;
  }
}

// ============================ CSR build ====================================
__global__ __launch_bounds__(256) void zero_counts_kernel(int* __restrict__ c, int n) {
  int i = blockIdx.x * 256 + threadIdx.x;
  if (i < n) c[i] = 0;
}

__global__ __launch_bounds__(256) void hist_kernel(
    const int* __restrict__ dst, int* __restrict__ counts, int nE) {
  int e = blockIdx.x * 256 + threadIdx.x;
  if (e < nE) atomicAdd(&counts[dst[e]], 1);
}

__global__ __launch_bounds__(256) void scan_partial_kernel(
    const int* __restrict__ counts, int* __restrict__ chunk_sum, int n) {
  __shared__ int sdata[256];
  int b = blockIdx.x, t = threadIdx.x;
  int base = b * CHUNK + t * 4;
  int s = 0;
#pragma unroll
  for (int k = 0; k < 4; ++k) {
    int i = base + k;
    if (i < n) s += counts[i];
  }
  sdata[t] = s;
  __syncthreads();
  for (int off = 128; off > 0; off >>= 1) {
    if (t < off) sdata[t] += sdata[t + off];
    __syncthreads();
  }
  if (t == 0) chunk_sum[b] = sdata[0];
}

__global__ void scan_chunks_kernel(const int* __restrict__ chunk_sum,
                                   int* __restrict__ chunk_off,
                                   int* __restrict__ row_start, int nchunks, int n) {
  if (threadIdx.x == 0 && blockIdx.x == 0) {
    int run = 0;
    for (int i = 0; i < nchunks; ++i) {
      chunk_off[i] = run;
      run += chunk_sum[i];
    }
    row_start[n] = run;
  }
}

__global__ __launch_bounds__(256) void scan_final_kernel(
    const int* __restrict__ counts, const int* __restrict__ chunk_off,
    int* __restrict__ row_start, int* __restrict__ cursor, int n) {
  __shared__ int sdata[256];
  int b = blockIdx.x, t = threadIdx.x;
  int base = b * CHUNK + t * 4;
  int c[4] = {0, 0, 0, 0};
#pragma unroll
  for (int k = 0; k < 4; ++k) {
    int i = base + k;
    if (i < n) c[k] = counts[i];
  }
  int tsum = c[0] + c[1] + c[2] + c[3];
  sdata[t] = tsum;
  __syncthreads();
  for (int off = 1; off < 256; off <<= 1) {
    int v = (t >= off) ? sdata[t - off] : 0;
    __syncthreads();
    sdata[t] += v;
    __syncthreads();
  }
  int run = sdata[t] - tsum + chunk_off[b];  // exclusive prefix
#pragma unroll
  for (int k = 0; k < 4; ++k) {
    int i = base + k;
    if (i < n) {
      row_start[i] = run;
      cursor[i] = run;
      run += c[k];
    }
  }
}

// one 8B store per edge: (src, adj-bits)
__global__ __launch_bounds__(256) void scatter_sort_kernel(
    const int* __restrict__ src, const int* __restrict__ dst,
    const float* __restrict__ adj, int* __restrict__ cursor,
    int2* __restrict__ edges, int nE) {
  int e = blockIdx.x * 256 + threadIdx.x;
  if (e >= nE) return;
  int d = dst[e];
  int2 ev;
  ev.x = src[e];
  ev.y = __float_as_int(adj[e]);
  int pos = atomicAdd(&cursor[d], 1);
  edges[pos] = ev;
}

// ===================== Gather, bf16 table (atomic-free) ====================
// 32 lanes per node; lane q owns cols 4q..4q+3 (one uint2 = 4 bf16).
__global__ __launch_bounds__(256) void gather_bf16_kernel(
    const uint2* __restrict__ xb, const int* __restrict__ row_start,
    const int2* __restrict__ edges, float* __restrict__ out, int nNodes) {
  int g = (blockIdx.x * 256 + threadIdx.x) >> 5;
  int q = threadIdx.x & 31;
  if (g >= nNodes) return;
  int beg = row_start[g], end = row_start[g + 1];
  float4 acc = make_float4(0.f, 0.f, 0.f, 0.f);
  int j = beg;
  for (; j + 1 < end; j += 2) {
    int2 e0 = edges[j], e1 = edges[j + 1];
    float a0 = __int_as_float(e0.y), a1 = __int_as_float(e1.y);
    uint2 v0 = xb[(size_t)e0.x * 32 + q];
    uint2 v1 = xb[(size_t)e1.x * 32 + q];
    acc.x = fmaf(a0, __uint_as_float(v0.x << 16), acc.x);
    acc.y = fmaf(a0, __uint_as_float(v0.x & 0xffff0000u), acc.y);
    acc.z = fmaf(a0, __uint_as_float(v0.y << 16), acc.z);
    acc.w = fmaf(a0, __uint_as_float(v0.y & 0xffff0000u), acc.w);
    acc.x = fmaf(a1, __uint_as_float(v1.x << 16), acc.x);
    acc.y = fmaf(a1, __uint_as_float(v1.x & 0xffff0000u), acc.y);
    acc.z = fmaf(a1, __uint_as_float(v1.y << 16), acc.z);
    acc.w = fmaf(a1, __uint_as_float(v1.y & 0xffff0000u), acc.w);
  }
  if (j < end) {
    int2 e0 = edges[j];
    float a0 = __int_as_float(e0.y);
    uint2 v0 = xb[(size_t)e0.x * 32 + q];
    acc.x = fmaf(a0, __uint_as_float(v0.x << 16), acc.x);
    acc.y = fmaf(a0, __uint_as_float(v0.x & 0xffff0000u), acc.y);
    acc.z = fmaf(a0, __uint_as_float(v0.y << 16), acc.z);
    acc.w = fmaf(a0, __uint_as_float(v0.y & 0xffff0000u), acc.w);
  }
  ((float4*)out)[(size_t)g * 32 + q] = acc;
}

// ===================== Gather, fp32 table (middle tier) ====================
__global__ __launch_bounds__(256) void gather_fp32_kernel(
    const float* __restrict__ x, const int* __restrict__ row_start,
    const int2* __restrict__ edges, float* __restrict__ out, int nNodes) {
  int g = (blockIdx.x * 256 + threadIdx.x) >> 5;
  int q = threadIdx.x & 31;
  if (g >= nNodes) return;
  int beg = row_start[g], end = row_start[g + 1];
  const float4* x4 = (const float4*)x;
  float4 acc = make_float4(0.f, 0.f, 0.f, 0.f);
  int j = beg;
  for (; j + 1 < end; j += 2) {
    int2 e0 = edges[j], e1 = edges[j + 1];
    float a0 = __int_as_float(e0.y), a1 = __int_as_float(e1.y);
    float4 v0 = x4[(size_t)e0.x * 32 + q];
    float4 v1 = x4[(size_t)e1.x * 32 + q];
    acc.x = fmaf(a0, v0.x, acc.x); acc.y = fmaf(a0, v0.y, acc.y);
    acc.z = fmaf(a0, v0.z, acc.z); acc.w = fmaf(a0, v0.w, acc.w);
    acc.x = fmaf(a1, v1.x, acc.x); acc.y = fmaf(a1, v1.y, acc.y);
    acc.z = fmaf(a1, v1.z, acc.z); acc.w = fmaf(a1, v1.w, acc.w);
  }
  if (j < end) {
    int2 e0 = edges[j];
    float a0 = __int_as_float(e0.y);
    float4 v0 = x4[(size_t)e0.x * 32 + q];
    acc.x = fmaf(a0, v0.x, acc.x); acc.y = fmaf(a0, v0.y, acc.y);
    acc.z = fmaf(a0, v0.z, acc.z); acc.w = fmaf(a0, v0.w, acc.w);
  }
  ((float4*)out)[(size_t)g * 32 + q] = acc;
}

// ============================ Fallback (atomic path) =======================
__global__ __launch_bounds__(256) void zero_kernel(float4* __restrict__ out, int n4) {
  int i = blockIdx.x * 256 + threadIdx.x;
  if (i < n4) out[i] = make_float4(0.f, 0.f, 0.f, 0.f);
}

__global__ __launch_bounds__(256) void scatter_atomic_kernel(
    const float* __restrict__ x, const int* __restrict__ src,
    const int* __restrict__ dst, const float* __restrict__ adj,
    float* __restrict__ out, int nE) {
  int tid = blockIdx.x * 256 + threadIdx.x;
  int e = tid >> 5;
  int q = tid & 31;
  if (e >= nE) return;
  int s = src[e];
  int d = dst[e];
  float a = adj[e];
  float4 v = ((const float4*)x)[(size_t)s * 32 + q];
  float* o = out + (size_t)d * D + q * 4;
  atomicAdd(o + 0, v.x * a);
  atomicAdd(o + 1, v.y * a);
  atomicAdd(o + 2, v.z * a);
  atomicAdd(o + 3, v.w * a);
}

// ============================ Fused GEMM epilogue ==========================
// out[r,:] = relu(out[r,:] @ W + y[r,:] + b). Row-local, in-place.
__global__ __launch_bounds__(256) void gemm_fused_kernel(
    float* __restrict__ out, const float* __restrict__ w,
    const float* __restrict__ y, const float* __restrict__ bias, int nrows) {
  __shared__ float sW[D * D];   // 64 KB
  __shared__ float sA[32 * D];  // 16 KB
  const int tid = threadIdx.x;
  const int row0 = blockIdx.x * 32;

  const float4* w4 = (const float4*)w;
  float4* sW4 = (float4*)sW;
  for (int i = tid; i < D * D / 4; i += 256) sW4[i] = w4[i];

  const int nrow_blk = min(32, nrows - row0);
  const float4* out4_base = (const float4*)(out + (size_t)row0 * D);
  float4* sA4 = (float4*)sA;
  for (int i = tid; i < nrow_blk * 32; i += 256) sA4[i] = out4_base[i];
  __syncthreads();

  const int cg = tid & 31;
  const int rs = tid >> 5;

  float4 acc[4];
#pragma unroll
  for (int r = 0; r < 4; ++r) acc[r] = make_float4(0.f, 0.f, 0.f, 0.f);

#pragma unroll 4
  for (int k4 = 0; k4 < 32; ++k4) {
    float4 wv0 = sW4[(k4 * 4 + 0) * 32 + cg];
    float4 wv1 = sW4[(k4 * 4 + 1) * 32 + cg];
    float4 wv2 = sW4[(k4 * 4 + 2) * 32 + cg];
    float4 wv3 = sW4[(k4 * 4 + 3) * 32 + cg];
#pragma unroll
    for (int r = 0; r < 4; ++r) {
      float4 xv = sA4[(rs + r * 8) * 32 + k4];
      acc[r].x = fmaf(xv.x, wv0.x, acc[r].x);
      acc[r].y = fmaf(xv.x, wv0.y, acc[r].y);
      acc[r].z = fmaf(xv.x, wv0.z, acc[r].z);
      acc[r].w = fmaf(xv.x, wv0.w, acc[r].w);
      acc[r].x = fmaf(xv.y, wv1.x, acc[r].x);
      acc[r].y = fmaf(xv.y, wv1.y, acc[r].y);
      acc[r].z = fmaf(xv.y, wv1.z, acc[r].z);
      acc[r].w = fmaf(xv.y, wv1.w, acc[r].w);
      acc[r].x = fmaf(xv.z, wv2.x, acc[r].x);
      acc[r].y = fmaf(xv.z, wv2.y, acc[r].y);
      acc[r].z = fmaf(xv.z, wv2.z, acc[r].z);
      acc[r].w = fmaf(xv.z, wv2.w, acc[r].w);
      acc[r].x = fmaf(xv.w, wv3.x, acc[r].x);
      acc[r].y = fmaf(xv.w, wv3.y, acc[r].y);
      acc[r].z = fmaf(xv.w, wv3.z, acc[r].z);
      acc[r].w = fmaf(xv.w, wv3.w, acc[r].w);
    }
  }

  const float4* y4 = (const float4*)y;
  const float4* b4 = (const float4*)bias;
  float4* o4 = (float4*)out;
  float4 bv = b4[cg];
#pragma unroll
  for (int r = 0; r < 4; ++r) {
    int row = row0 + rs + r * 8;
    if (row < nrows) {
      float4 yv = y4[(size_t)row * 32 + cg];
      float4 res;
      res.x = fmaxf(acc[r].x + yv.x + bv.x, 0.f);
      res.y = fmaxf(acc[r].y + yv.y + bv.y, 0.f);
      res.z = fmaxf(acc[r].z + yv.z + bv.z, 0.f);
      res.w = fmaxf(acc[r].w + yv.w + bv.w, 0.f);
      o4[(size_t)row * 32 + cg] = res;
    }
  }
}

extern "C" void kernel_launch(void* const* d_in, const int* in_sizes, int n_in,
                              void* d_out, int out_size, void* d_ws, size_t ws_size,
                              hipStream_t stream) {
  const float* x    = (const float*)d_in[0];
  const float* y    = (const float*)d_in[1];
  const int*   esrc = (const int*)d_in[2];
  const int*   edst = (const int*)d_in[3];
  const float* adj  = (const float*)d_in[4];
  const float* w    = (const float*)d_in[5];
  const float* bias = (const float*)d_in[6];
  float* out = (float*)d_out;

  const int nNodes = in_sizes[0] / D;
  const int nE = in_sizes[2];
  const int n4 = nNodes * (D / 4);
  const int nchunks = (nNodes + CHUNK - 1) / CHUNK;

  const size_t xb_bytes   = (size_t)nNodes * D * 2;            // bf16 table
  const size_t edge_bytes = (size_t)nE * 8;                    // int2 records
  const size_t int_bytes  = (size_t)(3 * nNodes + 1 + 2 * nchunks) * 4;
  const size_t need_bf16  = xb_bytes + edge_bytes + int_bytes;
  const size_t need_fp32  = edge_bytes + int_bytes;

  if (ws_size >= need_bf16) {
    char* base      = (char*)d_ws;
    ushort4* xb4    = (ushort4*)base;
    int2* edges     = (int2*)(base + xb_bytes);
    int* counts     = (int*)(base + xb_bytes + edge_bytes);
    int* row_start  = counts + nNodes;
    int* cursor     = row_start + nNodes + 1;
    int* chunk_sum  = cursor + nNodes;
    int* chunk_off  = chunk_sum + nchunks;

    convert_zero_kernel<<<(n4 + 255) / 256, 256, 0, stream>>>(
        (const float4*)x, xb4, n4, counts, nNodes);
    hist_kernel<<<(nE + 255) / 256, 256, 0, stream>>>(edst, counts, nE);
    scan_partial_kernel<<<nchunks, 256, 0, stream>>>(counts, chunk_sum, nNodes);
    scan_chunks_kernel<<<1, 64, 0, stream>>>(chunk_sum, chunk_off, row_start,
                                             nchunks, nNodes);
    scan_final_kernel<<<nchunks, 256, 0, stream>>>(counts, chunk_off, row_start,
                                                   cursor, nNodes);
    scatter_sort_kernel<<<(nE + 255) / 256, 256, 0, stream>>>(
        esrc, edst, adj, cursor, edges, nE);
    gather_bf16_kernel<<<(nNodes * 32 + 255) / 256, 256, 0, stream>>>(
        (const uint2*)xb4, row_start, edges, out, nNodes);
  } else if (ws_size >= need_fp32) {
    char* base      = (char*)d_ws;
    int2* edges     = (int2*)base;
    int* counts     = (int*)(base + edge_bytes);
    int* row_start  = counts + nNodes;
    int* cursor     = row_start + nNodes + 1;
    int* chunk_sum  = cursor + nNodes;
    int* chunk_off  = chunk_sum + nchunks;

    zero_counts_kernel<<<(nNodes + 255) / 256, 256, 0, stream>>>(counts, nNodes);
    hist_kernel<<<(nE + 255) / 256, 256, 0, stream>>>(edst, counts, nE);
    scan_partial_kernel<<<nchunks, 256, 0, stream>>>(counts, chunk_sum, nNodes);
    scan_chunks_kernel<<<1, 64, 0, stream>>>(chunk_sum, chunk_off, row_start,
                                             nchunks, nNodes);
    scan_final_kernel<<<nchunks, 256, 0, stream>>>(counts, chunk_off, row_start,
                                                   cursor, nNodes);
    scatter_sort_kernel<<<(nE + 255) / 256, 256, 0, stream>>>(
        esrc, edst, adj, cursor, edges, nE);
    gather_fp32_kernel<<<(nNodes * 32 + 255) / 256, 256, 0, stream>>>(
        x, row_start, edges, out, nNodes);
  } else {
    zero_kernel<<<(n4 + 255) / 256, 256, 0, stream>>>((float4*)out, n4);
    scatter_atomic_kernel<<<((size_t)nE * 32 + 255) / 256, 256, 0, stream>>>(
        x, esrc, edst, adj, out, nE);
  }
  gemm_fused_kernel<<<(nNodes + 31) / 32, 256, 0, stream>>>(out, w, y, bias, nNodes);
}